// Round 14
// baseline (134.832 us; speedup 1.0000x reference)
//
#include <hip/hip_runtime.h>
#include <math.h>

typedef __attribute__((ext_vector_type(8))) short bf16x8;
typedef __attribute__((ext_vector_type(4))) float f32x4;
typedef unsigned short u16;

__device__ __forceinline__ unsigned short f2bf(float f) {
    unsigned u = __builtin_bit_cast(unsigned, f);
    u += 0x7fffu + ((u >> 16) & 1u);          // round-to-nearest-even
    return (unsigned short)(u >> 16);
}

// ---------------------------------------------------------------------------
// Prep 1: sin/cos table for all MZIs of all 3 meshes (+ pack P4 from W).
// P4 k-rows now INTERLEAVED: k=2j -> re of feature j, k=2j+1 -> im.
// ---------------------------------------------------------------------------
__global__ __launch_bounds__(128) void prep_trig_kernel(
    const float* __restrict__ mzi1, const float* __restrict__ mzi2,
    const float* __restrict__ mzi3, const float* __restrict__ W,
    float4* __restrict__ trig, u16* __restrict__ P4)
{
    const int b = blockIdx.x, t = threadIdx.x;
    if (b < 384) {
        if (t >= 64) return;
        const int s = b >> 7, L = b & 127;
        const float* mzi = (s == 0) ? mzi1 : ((s == 1) ? mzi2 : mzi3);
        const int start = L & 1;
        const int m = (128 - start) >> 1;
        float4 v = make_float4(1.f, 0.f, 1.f, 0.f);
        if (t < m) {
            const int off = (L >> 1) * 254 + start * 128 + 2 * t;
            float th = mzi[off], ph = mzi[off + 1];
            float st, ct, sp, cp;
            __sincosf(th, &st, &ct);
            __sincosf(ph, &sp, &cp);
            v = make_float4(ct, st, cp, sp);
        }
        trig[b * 64 + t] = v;
    } else {
        const int n = b - 384;           // output col 0..127
        const int j = t;                  // complex feature 0..127
        P4[n * 256 + 2 * j]     = f2bf(W[n * 256 + j]);
        P4[n * 256 + 2 * j + 1] = f2bf(W[n * 256 + j + 128]);
    }
}

// ---------------------------------------------------------------------------
// Prep 2: build row r of mesh s via register+shuffle layer composition.
// P1: [256 cols][128 k] (k = raw x feature, unchanged).
// P2,P3: [256 cols][256 k], k-rows INTERLEAVED (k=2r re, 2r+1 im of input
// feature r) to match the new z LDS layout. Output cols (cre) unchanged
// (fixed by MFMA C-layout / nofu pairing).
// ---------------------------------------------------------------------------
__global__ __launch_bounds__(64) void build_pack_kernel(
    const float* __restrict__ inph,
    const float* __restrict__ outph1, const float* __restrict__ outph2,
    const float* __restrict__ outph3,
    const float4* __restrict__ trig,
    u16* __restrict__ P1, u16* __restrict__ P2, u16* __restrict__ P3)
{
    const int s = blockIdx.x >> 7, r = blockIdx.x & 127, t = threadIdx.x;
    const float4* tg = trig + s * 128 * 64;

    float2 a = make_float2(0.f, 0.f), b2 = make_float2(0.f, 0.f);
    if (s == 0) {
        float sp, cp; __sincosf(inph[r], &sp, &cp);
        if (2 * t == r)     a  = make_float2(cp, sp);
        if (2 * t + 1 == r) b2 = make_float2(cp, sp);
    } else {
        if (2 * t == r)     a.x  = 1.f;
        if (2 * t + 1 == r) b2.x = 1.f;
    }

    float4 tv[4];
    #pragma unroll
    for (int i = 0; i < 4; ++i) tv[i] = tg[i * 64 + t];

    #pragma unroll 4
    for (int L = 0; L < 128; ++L) {
        const float4 c = tv[L & 3];
        if (L < 124) tv[L & 3] = tg[(L + 4) * 64 + t];
        if ((L & 1) == 0) {
            float pr = c.x * (a.x * c.z - a.y * c.w) + c.y * b2.x;
            float pi = c.x * (a.x * c.w + a.y * c.z) + c.y * b2.y;
            float qr = c.y * a.x - c.x * (b2.x * c.z + b2.y * c.w);
            float qi = c.y * a.y - c.x * (b2.y * c.z - b2.x * c.w);
            a = make_float2(pr, pi); b2 = make_float2(qr, qi);
        } else {
            float2 an;
            an.x = __shfl_down(a.x, 1); an.y = __shfl_down(a.y, 1);
            float pr = c.x * (b2.x * c.z - b2.y * c.w) + c.y * an.x;
            float pi = c.x * (b2.x * c.w + b2.y * c.z) + c.y * an.y;
            float qr = c.y * b2.x - c.x * (an.x * c.z + an.y * c.w);
            float qi = c.y * b2.y - c.x * (an.y * c.z - an.x * c.w);
            if (t < 63) b2 = make_float2(pr, pi);
            float2 qs;
            qs.x = __shfl_up(qr, 1); qs.y = __shfl_up(qi, 1);
            if (t >= 1) a = qs;
        }
    }

    const float* outph = (s == 0) ? outph1 : ((s == 1) ? outph2 : outph3);
    #pragma unroll
    for (int h = 0; h < 2; ++h) {
        const int j = 2 * t + h;
        float2 w = h ? b2 : a;
        float sp, cp; __sincosf(outph[j], &sp, &cp);
        const float wr = w.x * cp - w.y * sp;
        const float wi = w.x * sp + w.y * cp;
        const int cre = ((j >> 4) * 32) + (j & 15);
        if (s == 0) {
            P1[cre * 128 + r]        = f2bf(wr);
            P1[(cre + 16) * 128 + r] = f2bf(wi);
        } else {
            u16* P = (s == 1) ? P2 : P3;
            P[cre * 256 + 2 * r]            = f2bf(wr);
            P[cre * 256 + 2 * r + 1]        = f2bf(-wi);
            P[(cre + 16) * 256 + 2 * r]     = f2bf(wi);
            P[(cre + 16) * 256 + 2 * r + 1] = f2bf(wr);
        }
    }
}

// ---------------------------------------------------------------------------
// Main fused kernel, R14: WAVE-INDEPENDENT pipeline. 1 wave (64 thr) per
// block, 32 batch rows per wave, ZERO barriers. The inter-stage all-to-all
// is feature-wise per row, so a wave owning 32 rows x all 256 features is
// self-contained: x->regs, stage1 (2 passes of 128 cols, acc[2][8]=64 regs),
// nofu, transpose into a PRIVATE 16KB LDS tile (z stored interleaved
// [row][2f]=re,[2f+1]=im -> packed b32 writes), stages 2/3 likewise with
// pass-0 output HELD in 32 packed regs until pass-1's LDS reads finish
// (avoids double-buffering), final matmul, store. No __syncthreads at all;
// 8 independent waves/CU decorrelate every stall (R13's 8-barrier phase
// lockstep was the 84us wall: all pipes sum to ~40us).
// (64,2): 256-reg budget, demand ~150 -> no spill expected.
// sched_barrier+lgkmcnt fences guard LDS write->read boundaries (rule #18).
// ---------------------------------------------------------------------------
__global__ __launch_bounds__(64, 2) void ficonn_mfma_kernel(
    const float* __restrict__ x,
    const u16* __restrict__ P1, const u16* __restrict__ P2,
    const u16* __restrict__ P3, const u16* __restrict__ P4,
    const float* __restrict__ al1, const float* __restrict__ be1,
    const float* __restrict__ al2, const float* __restrict__ be2,
    const float* __restrict__ bias, float* __restrict__ out)
{
    __shared__ __align__(16) char zA[16384];   // [32 rows][256 k] bf16, swizzled

    const int lane = threadIdx.x;      // single wave
    const int l16  = lane & 15;
    const int kg   = lane >> 4;
    const size_t rowBase = (size_t)blockIdx.x * 32;

    // ---- load x as 8 A-fragments (2 mt x 4 ks), fp32 -> bf16 in regs ----
    bf16x8 xf[2][4];
    #pragma unroll
    for (int mt = 0; mt < 2; ++mt)
        #pragma unroll
        for (int ks = 0; ks < 4; ++ks) {
            const float* px = x + (rowBase + mt * 16 + l16) * 128 + ks * 32 + kg * 8;
            float4 f0 = *(const float4*)px;
            float4 f1 = *(const float4*)(px + 4);
            bf16x8 t;
            t[0] = (short)f2bf(f0.x); t[1] = (short)f2bf(f0.y);
            t[2] = (short)f2bf(f0.z); t[3] = (short)f2bf(f0.w);
            t[4] = (short)f2bf(f1.x); t[5] = (short)f2bf(f1.y);
            t[6] = (short)f2bf(f1.z); t[7] = (short)f2bf(f1.w);
            xf[mt][ks] = t;
        }

    f32x4 acc[2][8];

    // ================= stage 1: z1 = x @ P1 (K=128), 2 passes ==============
    #pragma unroll
    for (int p = 0; p < 2; ++p) {
        #pragma unroll
        for (int mt = 0; mt < 2; ++mt)
            #pragma unroll
            for (int nt = 0; nt < 8; ++nt) acc[mt][nt] = (f32x4){0.f, 0.f, 0.f, 0.f};

        #pragma unroll
        for (int ks = 0; ks < 4; ++ks)
            #pragma unroll
            for (int nt = 0; nt < 8; ++nt) {
                bf16x8 Bf = *(const bf16x8*)&P1[(p * 128 + nt * 16 + l16) * 128 + ks * 32 + kg * 8];
                acc[0][nt] = __builtin_amdgcn_mfma_f32_16x16x32_bf16(xf[0][ks], Bf, acc[0][nt], 0, 0, 0);
                acc[1][nt] = __builtin_amdgcn_mfma_f32_16x16x32_bf16(xf[1][ks], Bf, acc[1][nt], 0, 0, 0);
            }

        // nofu1 + write to zA (interleaved: [row][4*f] packed re|im)
        #pragma unroll
        for (int u = 0; u < 4; ++u) {
            const int fb = (p * 4 + u) * 16 + l16;      // feature index
            const float av = 0.5f * fminf(fmaxf(al1[fb], 0.f), 10.f);
            const float bv = fminf(fmaxf(be1[fb], 0.f), 10.f);
            #pragma unroll
            for (int mt = 0; mt < 2; ++mt)
                #pragma unroll
                for (int r = 0; r < 4; ++r) {
                    float re = acc[mt][2 * u][r], im = acc[mt][2 * u + 1][r];
                    float I = fmaf(re, re, fmaf(im, im, 1e-8f));
                    float fct = __expf(-av / fmaf(bv, I, 1.f));
                    re *= fct; im *= fct;
                    unsigned pk = (unsigned)f2bf(re) | ((unsigned)f2bf(im) << 16);
                    const int row = mt * 16 + kg * 4 + r;
                    const unsigned byte = ((unsigned)(row * 512 + fb * 4)) ^ ((unsigned)(row & 31) << 4);
                    *(unsigned*)(zA + byte) = pk;
                }
        }
    }
    asm volatile("s_waitcnt lgkmcnt(0)" ::: "memory");
    __builtin_amdgcn_sched_barrier(0);

    // ================= stages 2,3: z = nofu?(z @ P), K=256, 2 passes ========
    #pragma unroll
    for (int s = 0; s < 2; ++s) {
        const u16* P = (s == 0) ? P2 : P3;
        unsigned hold[2][4][4];            // pass-0 packed output, deferred

        #pragma unroll
        for (int p = 0; p < 2; ++p) {
            #pragma unroll
            for (int mt = 0; mt < 2; ++mt)
                #pragma unroll
                for (int nt = 0; nt < 8; ++nt) acc[mt][nt] = (f32x4){0.f, 0.f, 0.f, 0.f};

            #pragma unroll
            for (int ks = 0; ks < 8; ++ks) {
                bf16x8 A0, A1;
                {
                    const int row0 = l16;
                    const unsigned b0 = ((unsigned)(row0 * 512 + ks * 64 + kg * 16)) ^ ((unsigned)row0 << 4);
                    A0 = *(const bf16x8*)(zA + b0);
                    const int row1 = 16 + l16;
                    const unsigned b1 = ((unsigned)(row1 * 512 + ks * 64 + kg * 16)) ^ ((unsigned)row1 << 4);
                    A1 = *(const bf16x8*)(zA + b1);
                }
                #pragma unroll
                for (int nt = 0; nt < 8; ++nt) {
                    bf16x8 Bf = *(const bf16x8*)&P[(p * 128 + nt * 16 + l16) * 256 + ks * 32 + kg * 8];
                    acc[0][nt] = __builtin_amdgcn_mfma_f32_16x16x32_bf16(A0, Bf, acc[0][nt], 0, 0, 0);
                    acc[1][nt] = __builtin_amdgcn_mfma_f32_16x16x32_bf16(A1, Bf, acc[1][nt], 0, 0, 0);
                }
            }

            // nofu (stage 2 only) + pack; pass 0 held, pass 1 written
            #pragma unroll
            for (int u = 0; u < 4; ++u) {
                const int fb = (p * 4 + u) * 16 + l16;
                float av = 0.f, bv = 0.f;
                if (s == 0) {
                    av = 0.5f * fminf(fmaxf(al2[fb], 0.f), 10.f);
                    bv = fminf(fmaxf(be2[fb], 0.f), 10.f);
                }
                #pragma unroll
                for (int mt = 0; mt < 2; ++mt)
                    #pragma unroll
                    for (int r = 0; r < 4; ++r) {
                        float re = acc[mt][2 * u][r], im = acc[mt][2 * u + 1][r];
                        if (s == 0) {
                            float I = fmaf(re, re, fmaf(im, im, 1e-8f));
                            float fct = __expf(-av / fmaf(bv, I, 1.f));
                            re *= fct; im *= fct;
                        }
                        unsigned pk = (unsigned)f2bf(re) | ((unsigned)f2bf(im) << 16);
                        if (p == 0) {
                            hold[mt][u][r] = pk;
                        } else {
                            const int row = mt * 16 + kg * 4 + r;
                            const unsigned byte = ((unsigned)(row * 512 + fb * 4)) ^ ((unsigned)(row & 31) << 4);
                            *(unsigned*)(zA + byte) = pk;
                        }
                    }
            }
        }

        // all pass-1 LDS reads are done; now safe to overwrite cols 0..127
        __builtin_amdgcn_sched_barrier(0);
        #pragma unroll
        for (int u = 0; u < 4; ++u) {
            const int fb = u * 16 + l16;
            #pragma unroll
            for (int mt = 0; mt < 2; ++mt)
                #pragma unroll
                for (int r = 0; r < 4; ++r) {
                    const int row = mt * 16 + kg * 4 + r;
                    const unsigned byte = ((unsigned)(row * 512 + fb * 4)) ^ ((unsigned)(row & 31) << 4);
                    *(unsigned*)(zA + byte) = hold[mt][u][r];
                }
        }
        asm volatile("s_waitcnt lgkmcnt(0)" ::: "memory");
        __builtin_amdgcn_sched_barrier(0);
    }

    // ================= final: out = z3 @ P4 + bias (128 cols, 1 pass) =======
    #pragma unroll
    for (int mt = 0; mt < 2; ++mt)
        #pragma unroll
        for (int nt = 0; nt < 8; ++nt) acc[mt][nt] = (f32x4){0.f, 0.f, 0.f, 0.f};

    #pragma unroll
    for (int ks = 0; ks < 8; ++ks) {
        bf16x8 A0, A1;
        {
            const int row0 = l16;
            const unsigned b0 = ((unsigned)(row0 * 512 + ks * 64 + kg * 16)) ^ ((unsigned)row0 << 4);
            A0 = *(const bf16x8*)(zA + b0);
            const int row1 = 16 + l16;
            const unsigned b1 = ((unsigned)(row1 * 512 + ks * 64 + kg * 16)) ^ ((unsigned)row1 << 4);
            A1 = *(const bf16x8*)(zA + b1);
        }
        #pragma unroll
        for (int nt = 0; nt < 8; ++nt) {
            bf16x8 Bf = *(const bf16x8*)&P4[(nt * 16 + l16) * 256 + ks * 32 + kg * 8];
            acc[0][nt] = __builtin_amdgcn_mfma_f32_16x16x32_bf16(A0, Bf, acc[0][nt], 0, 0, 0);
            acc[1][nt] = __builtin_amdgcn_mfma_f32_16x16x32_bf16(A1, Bf, acc[1][nt], 0, 0, 0);
        }
    }

    #pragma unroll
    for (int nt = 0; nt < 8; ++nt) {
        const float bc = bias[nt * 16 + l16];
        #pragma unroll
        for (int mt = 0; mt < 2; ++mt)
            #pragma unroll
            for (int r = 0; r < 4; ++r) {
                const size_t row = rowBase + mt * 16 + kg * 4 + r;
                out[row * 128 + nt * 16 + l16] = acc[mt][nt][r] + bc;
            }
    }
}

extern "C" void kernel_launch(void* const* d_in, const int* in_sizes, int n_in,
                              void* d_out, int out_size, void* d_ws, size_t ws_size,
                              hipStream_t stream)
{
    const float* x      = (const float*)d_in[0];
    const float* inph   = (const float*)d_in[1];
    const float* mzi1   = (const float*)d_in[2];
    const float* outph1 = (const float*)d_in[3];
    const float* alpha1 = (const float*)d_in[4];
    const float* beta1  = (const float*)d_in[5];
    const float* mzi2   = (const float*)d_in[6];
    const float* outph2 = (const float*)d_in[7];
    const float* alpha2 = (const float*)d_in[8];
    const float* beta2  = (const float*)d_in[9];
    const float* mzi3   = (const float*)d_in[10];
    const float* outph3 = (const float*)d_in[11];
    const float* W      = (const float*)d_in[12];
    const float* bias   = (const float*)d_in[13];

    const int B = in_sizes[0] / 128;

    // ws layout
    float4* trig = (float4*)d_ws;                          // 3*128*64*16 = 393216 B
    u16* P1 = (u16*)((char*)d_ws + 393216);                // 65536 B
    u16* P2 = P1 + 32768;                                  // 131072 B
    u16* P3 = P2 + 65536;                                  // 131072 B
    u16* P4 = P3 + 65536;                                  // 65536 B

    prep_trig_kernel<<<512, 128, 0, stream>>>(mzi1, mzi2, mzi3, W, trig, P4);
    build_pack_kernel<<<384, 64, 0, stream>>>(inph, outph1, outph2, outph3, trig, P1, P2, P3);
    ficonn_mfma_kernel<<<B / 32, 64, 0, stream>>>(
        x, P1, P2, P3, P4, alpha1, beta1, alpha2, beta2, bias, (float*)d_out);
}

// Round 15
// 134.457 us; speedup vs baseline: 1.0028x; 1.0028x over previous
//
#include <hip/hip_runtime.h>
#include <math.h>

typedef __attribute__((ext_vector_type(8))) short bf16x8;
typedef __attribute__((ext_vector_type(4))) float f32x4;
typedef unsigned short u16;

__device__ __forceinline__ unsigned short f2bf(float f) {
    unsigned u = __builtin_bit_cast(unsigned, f);
    u += 0x7fffu + ((u >> 16) & 1u);          // round-to-nearest-even
    return (unsigned short)(u >> 16);
}

// ---------------------------------------------------------------------------
// Prep 1: sin/cos table for all MZIs of all 3 meshes (+ pack P4 from W).
// P4 k-rows now INTERLEAVED: k=2j -> re of feature j, k=2j+1 -> im.
// ---------------------------------------------------------------------------
__global__ __launch_bounds__(128) void prep_trig_kernel(
    const float* __restrict__ mzi1, const float* __restrict__ mzi2,
    const float* __restrict__ mzi3, const float* __restrict__ W,
    float4* __restrict__ trig, u16* __restrict__ P4)
{
    const int b = blockIdx.x, t = threadIdx.x;
    if (b < 384) {
        if (t >= 64) return;
        const int s = b >> 7, L = b & 127;
        const float* mzi = (s == 0) ? mzi1 : ((s == 1) ? mzi2 : mzi3);
        const int start = L & 1;
        const int m = (128 - start) >> 1;
        float4 v = make_float4(1.f, 0.f, 1.f, 0.f);
        if (t < m) {
            const int off = (L >> 1) * 254 + start * 128 + 2 * t;
            float th = mzi[off], ph = mzi[off + 1];
            float st, ct, sp, cp;
            __sincosf(th, &st, &ct);
            __sincosf(ph, &sp, &cp);
            v = make_float4(ct, st, cp, sp);
        }
        trig[b * 64 + t] = v;
    } else {
        const int n = b - 384;           // output col 0..127
        const int j = t;                  // complex feature 0..127
        P4[n * 256 + 2 * j]     = f2bf(W[n * 256 + j]);
        P4[n * 256 + 2 * j + 1] = f2bf(W[n * 256 + j + 128]);
    }
}

// ---------------------------------------------------------------------------
// Prep 2: build row r of mesh s via register+shuffle layer composition.
// P1: [256 cols][128 k] (k = raw x feature, unchanged).
// P2,P3: [256 cols][256 k], k-rows INTERLEAVED (k=2r re, 2r+1 im of input
// feature r) to match the new z LDS layout. Output cols (cre) unchanged
// (fixed by MFMA C-layout / nofu pairing).
// ---------------------------------------------------------------------------
__global__ __launch_bounds__(64) void build_pack_kernel(
    const float* __restrict__ inph,
    const float* __restrict__ outph1, const float* __restrict__ outph2,
    const float* __restrict__ outph3,
    const float4* __restrict__ trig,
    u16* __restrict__ P1, u16* __restrict__ P2, u16* __restrict__ P3)
{
    const int s = blockIdx.x >> 7, r = blockIdx.x & 127, t = threadIdx.x;
    const float4* tg = trig + s * 128 * 64;

    float2 a = make_float2(0.f, 0.f), b2 = make_float2(0.f, 0.f);
    if (s == 0) {
        float sp, cp; __sincosf(inph[r], &sp, &cp);
        if (2 * t == r)     a  = make_float2(cp, sp);
        if (2 * t + 1 == r) b2 = make_float2(cp, sp);
    } else {
        if (2 * t == r)     a.x  = 1.f;
        if (2 * t + 1 == r) b2.x = 1.f;
    }

    float4 tv[4];
    #pragma unroll
    for (int i = 0; i < 4; ++i) tv[i] = tg[i * 64 + t];

    #pragma unroll 4
    for (int L = 0; L < 128; ++L) {
        const float4 c = tv[L & 3];
        if (L < 124) tv[L & 3] = tg[(L + 4) * 64 + t];
        if ((L & 1) == 0) {
            float pr = c.x * (a.x * c.z - a.y * c.w) + c.y * b2.x;
            float pi = c.x * (a.x * c.w + a.y * c.z) + c.y * b2.y;
            float qr = c.y * a.x - c.x * (b2.x * c.z + b2.y * c.w);
            float qi = c.y * a.y - c.x * (b2.y * c.z - b2.x * c.w);
            a = make_float2(pr, pi); b2 = make_float2(qr, qi);
        } else {
            float2 an;
            an.x = __shfl_down(a.x, 1); an.y = __shfl_down(a.y, 1);
            float pr = c.x * (b2.x * c.z - b2.y * c.w) + c.y * an.x;
            float pi = c.x * (b2.x * c.w + b2.y * c.z) + c.y * an.y;
            float qr = c.y * b2.x - c.x * (an.x * c.z + an.y * c.w);
            float qi = c.y * b2.y - c.x * (an.y * c.z - an.x * c.w);
            if (t < 63) b2 = make_float2(pr, pi);
            float2 qs;
            qs.x = __shfl_up(qr, 1); qs.y = __shfl_up(qi, 1);
            if (t >= 1) a = qs;
        }
    }

    const float* outph = (s == 0) ? outph1 : ((s == 1) ? outph2 : outph3);
    #pragma unroll
    for (int h = 0; h < 2; ++h) {
        const int j = 2 * t + h;
        float2 w = h ? b2 : a;
        float sp, cp; __sincosf(outph[j], &sp, &cp);
        const float wr = w.x * cp - w.y * sp;
        const float wi = w.x * sp + w.y * cp;
        const int cre = ((j >> 4) * 32) + (j & 15);
        if (s == 0) {
            P1[cre * 128 + r]        = f2bf(wr);
            P1[(cre + 16) * 128 + r] = f2bf(wi);
        } else {
            u16* P = (s == 1) ? P2 : P3;
            P[cre * 256 + 2 * r]            = f2bf(wr);
            P[cre * 256 + 2 * r + 1]        = f2bf(-wi);
            P[(cre + 16) * 256 + 2 * r]     = f2bf(wi);
            P[(cre + 16) * 256 + 2 * r + 1] = f2bf(wr);
        }
    }
}

// ---------------------------------------------------------------------------
// Main fused kernel, R14: WAVE-INDEPENDENT pipeline. 1 wave (64 thr) per
// block, 32 batch rows per wave, ZERO barriers. The inter-stage all-to-all
// is feature-wise per row, so a wave owning 32 rows x all 256 features is
// self-contained: x->regs, stage1 (2 passes of 128 cols, acc[2][8]=64 regs),
// nofu, transpose into a PRIVATE 16KB LDS tile (z stored interleaved
// [row][2f]=re,[2f+1]=im -> packed b32 writes), stages 2/3 likewise with
// pass-0 output HELD in 32 packed regs until pass-1's LDS reads finish
// (avoids double-buffering), final matmul, store. No __syncthreads at all;
// 8 independent waves/CU decorrelate every stall (R13's 8-barrier phase
// lockstep was the 84us wall: all pipes sum to ~40us).
// (64,2): 256-reg budget, demand ~150 -> no spill expected.
// sched_barrier+lgkmcnt fences guard LDS write->read boundaries (rule #18).
// ---------------------------------------------------------------------------
__global__ __launch_bounds__(64, 2) void ficonn_mfma_kernel(
    const float* __restrict__ x,
    const u16* __restrict__ P1, const u16* __restrict__ P2,
    const u16* __restrict__ P3, const u16* __restrict__ P4,
    const float* __restrict__ al1, const float* __restrict__ be1,
    const float* __restrict__ al2, const float* __restrict__ be2,
    const float* __restrict__ bias, float* __restrict__ out)
{
    __shared__ __align__(16) char zA[16384];   // [32 rows][256 k] bf16, swizzled

    const int lane = threadIdx.x;      // single wave
    const int l16  = lane & 15;
    const int kg   = lane >> 4;
    const size_t rowBase = (size_t)blockIdx.x * 32;

    // ---- load x as 8 A-fragments (2 mt x 4 ks), fp32 -> bf16 in regs ----
    bf16x8 xf[2][4];
    #pragma unroll
    for (int mt = 0; mt < 2; ++mt)
        #pragma unroll
        for (int ks = 0; ks < 4; ++ks) {
            const float* px = x + (rowBase + mt * 16 + l16) * 128 + ks * 32 + kg * 8;
            float4 f0 = *(const float4*)px;
            float4 f1 = *(const float4*)(px + 4);
            bf16x8 t;
            t[0] = (short)f2bf(f0.x); t[1] = (short)f2bf(f0.y);
            t[2] = (short)f2bf(f0.z); t[3] = (short)f2bf(f0.w);
            t[4] = (short)f2bf(f1.x); t[5] = (short)f2bf(f1.y);
            t[6] = (short)f2bf(f1.z); t[7] = (short)f2bf(f1.w);
            xf[mt][ks] = t;
        }

    f32x4 acc[2][8];

    // ================= stage 1: z1 = x @ P1 (K=128), 2 passes ==============
    #pragma unroll
    for (int p = 0; p < 2; ++p) {
        #pragma unroll
        for (int mt = 0; mt < 2; ++mt)
            #pragma unroll
            for (int nt = 0; nt < 8; ++nt) acc[mt][nt] = (f32x4){0.f, 0.f, 0.f, 0.f};

        #pragma unroll
        for (int ks = 0; ks < 4; ++ks)
            #pragma unroll
            for (int nt = 0; nt < 8; ++nt) {
                bf16x8 Bf = *(const bf16x8*)&P1[(p * 128 + nt * 16 + l16) * 128 + ks * 32 + kg * 8];
                acc[0][nt] = __builtin_amdgcn_mfma_f32_16x16x32_bf16(xf[0][ks], Bf, acc[0][nt], 0, 0, 0);
                acc[1][nt] = __builtin_amdgcn_mfma_f32_16x16x32_bf16(xf[1][ks], Bf, acc[1][nt], 0, 0, 0);
            }

        // nofu1 + write to zA (interleaved: [row][4*f] packed re|im)
        #pragma unroll
        for (int u = 0; u < 4; ++u) {
            const int fb = (p * 4 + u) * 16 + l16;      // feature index
            const float av = 0.5f * fminf(fmaxf(al1[fb], 0.f), 10.f);
            const float bv = fminf(fmaxf(be1[fb], 0.f), 10.f);
            #pragma unroll
            for (int mt = 0; mt < 2; ++mt)
                #pragma unroll
                for (int r = 0; r < 4; ++r) {
                    float re = acc[mt][2 * u][r], im = acc[mt][2 * u + 1][r];
                    float I = fmaf(re, re, fmaf(im, im, 1e-8f));
                    float fct = __expf(-av / fmaf(bv, I, 1.f));
                    re *= fct; im *= fct;
                    unsigned pk = (unsigned)f2bf(re) | ((unsigned)f2bf(im) << 16);
                    const int row = mt * 16 + kg * 4 + r;
                    const unsigned byte = ((unsigned)(row * 512 + fb * 4)) ^ ((unsigned)(row & 31) << 4);
                    *(unsigned*)(zA + byte) = pk;
                }
        }
    }
    asm volatile("s_waitcnt lgkmcnt(0)" ::: "memory");
    __builtin_amdgcn_sched_barrier(0);

    // ================= stages 2,3: z = nofu?(z @ P), K=256, 2 passes ========
    #pragma unroll
    for (int s = 0; s < 2; ++s) {
        const u16* P = (s == 0) ? P2 : P3;
        unsigned hold[2][4][4];            // pass-0 packed output, deferred

        #pragma unroll
        for (int p = 0; p < 2; ++p) {
            #pragma unroll
            for (int mt = 0; mt < 2; ++mt)
                #pragma unroll
                for (int nt = 0; nt < 8; ++nt) acc[mt][nt] = (f32x4){0.f, 0.f, 0.f, 0.f};

            #pragma unroll
            for (int ks = 0; ks < 8; ++ks) {
                bf16x8 A0, A1;
                {
                    const int row0 = l16;
                    const unsigned b0 = ((unsigned)(row0 * 512 + ks * 64 + kg * 16)) ^ ((unsigned)row0 << 4);
                    A0 = *(const bf16x8*)(zA + b0);
                    const int row1 = 16 + l16;
                    const unsigned b1 = ((unsigned)(row1 * 512 + ks * 64 + kg * 16)) ^ ((unsigned)row1 << 4);
                    A1 = *(const bf16x8*)(zA + b1);
                }
                #pragma unroll
                for (int nt = 0; nt < 8; ++nt) {
                    bf16x8 Bf = *(const bf16x8*)&P[(p * 128 + nt * 16 + l16) * 256 + ks * 32 + kg * 8];
                    acc[0][nt] = __builtin_amdgcn_mfma_f32_16x16x32_bf16(A0, Bf, acc[0][nt], 0, 0, 0);
                    acc[1][nt] = __builtin_amdgcn_mfma_f32_16x16x32_bf16(A1, Bf, acc[1][nt], 0, 0, 0);
                }
            }

            // nofu (stage 2 only) + pack; pass 0 held, pass 1 written
            #pragma unroll
            for (int u = 0; u < 4; ++u) {
                const int fb = (p * 4 + u) * 16 + l16;
                float av = 0.f, bv = 0.f;
                if (s == 0) {
                    av = 0.5f * fminf(fmaxf(al2[fb], 0.f), 10.f);
                    bv = fminf(fmaxf(be2[fb], 0.f), 10.f);
                }
                #pragma unroll
                for (int mt = 0; mt < 2; ++mt)
                    #pragma unroll
                    for (int r = 0; r < 4; ++r) {
                        float re = acc[mt][2 * u][r], im = acc[mt][2 * u + 1][r];
                        if (s == 0) {
                            float I = fmaf(re, re, fmaf(im, im, 1e-8f));
                            float fct = __expf(-av / fmaf(bv, I, 1.f));
                            re *= fct; im *= fct;
                        }
                        unsigned pk = (unsigned)f2bf(re) | ((unsigned)f2bf(im) << 16);
                        if (p == 0) {
                            hold[mt][u][r] = pk;
                        } else {
                            const int row = mt * 16 + kg * 4 + r;
                            const unsigned byte = ((unsigned)(row * 512 + fb * 4)) ^ ((unsigned)(row & 31) << 4);
                            *(unsigned*)(zA + byte) = pk;
                        }
                    }
            }
        }

        // all pass-1 LDS reads are done; now safe to overwrite cols 0..127
        __builtin_amdgcn_sched_barrier(0);
        #pragma unroll
        for (int u = 0; u < 4; ++u) {
            const int fb = u * 16 + l16;
            #pragma unroll
            for (int mt = 0; mt < 2; ++mt)
                #pragma unroll
                for (int r = 0; r < 4; ++r) {
                    const int row = mt * 16 + kg * 4 + r;
                    const unsigned byte = ((unsigned)(row * 512 + fb * 4)) ^ ((unsigned)(row & 31) << 4);
                    *(unsigned*)(zA + byte) = hold[mt][u][r];
                }
        }
        asm volatile("s_waitcnt lgkmcnt(0)" ::: "memory");
        __builtin_amdgcn_sched_barrier(0);
    }

    // ================= final: out = z3 @ P4 + bias (128 cols, 1 pass) =======
    #pragma unroll
    for (int mt = 0; mt < 2; ++mt)
        #pragma unroll
        for (int nt = 0; nt < 8; ++nt) acc[mt][nt] = (f32x4){0.f, 0.f, 0.f, 0.f};

    #pragma unroll
    for (int ks = 0; ks < 8; ++ks) {
        bf16x8 A0, A1;
        {
            const int row0 = l16;
            const unsigned b0 = ((unsigned)(row0 * 512 + ks * 64 + kg * 16)) ^ ((unsigned)row0 << 4);
            A0 = *(const bf16x8*)(zA + b0);
            const int row1 = 16 + l16;
            const unsigned b1 = ((unsigned)(row1 * 512 + ks * 64 + kg * 16)) ^ ((unsigned)row1 << 4);
            A1 = *(const bf16x8*)(zA + b1);
        }
        #pragma unroll
        for (int nt = 0; nt < 8; ++nt) {
            bf16x8 Bf = *(const bf16x8*)&P4[(nt * 16 + l16) * 256 + ks * 32 + kg * 8];
            acc[0][nt] = __builtin_amdgcn_mfma_f32_16x16x32_bf16(A0, Bf, acc[0][nt], 0, 0, 0);
            acc[1][nt] = __builtin_amdgcn_mfma_f32_16x16x32_bf16(A1, Bf, acc[1][nt], 0, 0, 0);
        }
    }

    #pragma unroll
    for (int nt = 0; nt < 8; ++nt) {
        const float bc = bias[nt * 16 + l16];
        #pragma unroll
        for (int mt = 0; mt < 2; ++mt)
            #pragma unroll
            for (int r = 0; r < 4; ++r) {
                const size_t row = rowBase + mt * 16 + kg * 4 + r;
                out[row * 128 + nt * 16 + l16] = acc[mt][nt][r] + bc;
            }
    }
}

extern "C" void kernel_launch(void* const* d_in, const int* in_sizes, int n_in,
                              void* d_out, int out_size, void* d_ws, size_t ws_size,
                              hipStream_t stream)
{
    const float* x      = (const float*)d_in[0];
    const float* inph   = (const float*)d_in[1];
    const float* mzi1   = (const float*)d_in[2];
    const float* outph1 = (const float*)d_in[3];
    const float* alpha1 = (const float*)d_in[4];
    const float* beta1  = (const float*)d_in[5];
    const float* mzi2   = (const float*)d_in[6];
    const float* outph2 = (const float*)d_in[7];
    const float* alpha2 = (const float*)d_in[8];
    const float* beta2  = (const float*)d_in[9];
    const float* mzi3   = (const float*)d_in[10];
    const float* outph3 = (const float*)d_in[11];
    const float* W      = (const float*)d_in[12];
    const float* bias   = (const float*)d_in[13];

    const int B = in_sizes[0] / 128;

    // ws layout
    float4* trig = (float4*)d_ws;                          // 3*128*64*16 = 393216 B
    u16* P1 = (u16*)((char*)d_ws + 393216);                // 65536 B
    u16* P2 = P1 + 32768;                                  // 131072 B
    u16* P3 = P2 + 65536;                                  // 131072 B
    u16* P4 = P3 + 65536;                                  // 65536 B

    prep_trig_kernel<<<512, 128, 0, stream>>>(mzi1, mzi2, mzi3, W, trig, P4);
    build_pack_kernel<<<384, 64, 0, stream>>>(inph, outph1, outph2, outph3, trig, P1, P2, P3);
    ficonn_mfma_kernel<<<B / 32, 64, 0, stream>>>(
        x, P1, P2, P3, P4, alpha1, beta1, alpha2, beta2, bias, (float*)d_out);
}

// Round 16
// 86.262 us; speedup vs baseline: 1.5630x; 1.5587x over previous
//
#include <hip/hip_runtime.h>
#include <math.h>

typedef __attribute__((ext_vector_type(8))) short bf16x8;
typedef __attribute__((ext_vector_type(4))) float f32x4;
typedef unsigned short u16;

__device__ __forceinline__ unsigned short f2bf(float f) {
    unsigned u = __builtin_bit_cast(unsigned, f);
    u += 0x7fffu + ((u >> 16) & 1u);          // round-to-nearest-even
    return (unsigned short)(u >> 16);
}

// ---------------------------------------------------------------------------
// Prep 1: sin/cos table for all MZIs of all 3 meshes (+ pack P4 from W).
// ---------------------------------------------------------------------------
__global__ __launch_bounds__(128) void prep_trig_kernel(
    const float* __restrict__ mzi1, const float* __restrict__ mzi2,
    const float* __restrict__ mzi3, const float* __restrict__ W,
    float4* __restrict__ trig, u16* __restrict__ P4)
{
    const int b = blockIdx.x, t = threadIdx.x;
    if (b < 384) {
        if (t >= 64) return;
        const int s = b >> 7, L = b & 127;
        const float* mzi = (s == 0) ? mzi1 : ((s == 1) ? mzi2 : mzi3);
        const int start = L & 1;
        const int m = (128 - start) >> 1;
        float4 v = make_float4(1.f, 0.f, 1.f, 0.f);
        if (t < m) {
            const int off = (L >> 1) * 254 + start * 128 + 2 * t;
            float th = mzi[off], ph = mzi[off + 1];
            float st, ct, sp, cp;
            __sincosf(th, &st, &ct);
            __sincosf(ph, &sp, &cp);
            v = make_float4(ct, st, cp, sp);
        }
        trig[b * 64 + t] = v;
    } else {
        const int n = b - 384;           // output col 0..127
        const int j = t;                  // complex feature 0..127
        const int rre = ((j >> 4) * 32) + (j & 15);
        P4[n * 256 + rre]      = f2bf(W[n * 256 + j]);
        P4[n * 256 + rre + 16] = f2bf(W[n * 256 + j + 128]);
    }
}

// ---------------------------------------------------------------------------
// Prep 2: build row r of mesh s via register+shuffle layer composition,
// then pack to bf16 weight matrices in the block-16 interleaved real form.
// ---------------------------------------------------------------------------
__global__ __launch_bounds__(64) void build_pack_kernel(
    const float* __restrict__ inph,
    const float* __restrict__ outph1, const float* __restrict__ outph2,
    const float* __restrict__ outph3,
    const float4* __restrict__ trig,
    u16* __restrict__ P1, u16* __restrict__ P2, u16* __restrict__ P3)
{
    const int s = blockIdx.x >> 7, r = blockIdx.x & 127, t = threadIdx.x;
    const float4* tg = trig + s * 128 * 64;

    float2 a = make_float2(0.f, 0.f), b2 = make_float2(0.f, 0.f);
    if (s == 0) {
        float sp, cp; __sincosf(inph[r], &sp, &cp);
        if (2 * t == r)     a  = make_float2(cp, sp);
        if (2 * t + 1 == r) b2 = make_float2(cp, sp);
    } else {
        if (2 * t == r)     a.x  = 1.f;
        if (2 * t + 1 == r) b2.x = 1.f;
    }

    float4 tv[4];
    #pragma unroll
    for (int i = 0; i < 4; ++i) tv[i] = tg[i * 64 + t];

    #pragma unroll 4
    for (int L = 0; L < 128; ++L) {
        const float4 c = tv[L & 3];
        if (L < 124) tv[L & 3] = tg[(L + 4) * 64 + t];
        if ((L & 1) == 0) {
            float pr = c.x * (a.x * c.z - a.y * c.w) + c.y * b2.x;
            float pi = c.x * (a.x * c.w + a.y * c.z) + c.y * b2.y;
            float qr = c.y * a.x - c.x * (b2.x * c.z + b2.y * c.w);
            float qi = c.y * a.y - c.x * (b2.y * c.z - b2.x * c.w);
            a = make_float2(pr, pi); b2 = make_float2(qr, qi);
        } else {
            float2 an;
            an.x = __shfl_down(a.x, 1); an.y = __shfl_down(a.y, 1);
            float pr = c.x * (b2.x * c.z - b2.y * c.w) + c.y * an.x;
            float pi = c.x * (b2.x * c.w + b2.y * c.z) + c.y * an.y;
            float qr = c.y * b2.x - c.x * (an.x * c.z + an.y * c.w);
            float qi = c.y * b2.y - c.x * (an.y * c.z - an.x * c.w);
            if (t < 63) b2 = make_float2(pr, pi);
            float2 qs;
            qs.x = __shfl_up(qr, 1); qs.y = __shfl_up(qi, 1);
            if (t >= 1) a = qs;
        }
    }

    const float* outph = (s == 0) ? outph1 : ((s == 1) ? outph2 : outph3);
    #pragma unroll
    for (int h = 0; h < 2; ++h) {
        const int j = 2 * t + h;
        float2 w = h ? b2 : a;
        float sp, cp; __sincosf(outph[j], &sp, &cp);
        const float wr = w.x * cp - w.y * sp;
        const float wi = w.x * sp + w.y * cp;
        const int cre = ((j >> 4) * 32) + (j & 15);
        if (s == 0) {
            P1[cre * 128 + r]        = f2bf(wr);
            P1[(cre + 16) * 128 + r] = f2bf(wi);
        } else {
            u16* P = (s == 1) ? P2 : P3;
            const int rre = ((r >> 4) * 32) + (r & 15);
            P[cre * 256 + rre]             = f2bf(wr);
            P[cre * 256 + rre + 16]        = f2bf(-wi);
            P[(cre + 16) * 256 + rre]      = f2bf(wi);
            P[(cre + 16) * 256 + rre + 16] = f2bf(wr);
        }
    }
}

// ---------------------------------------------------------------------------
// Main fused kernel. R16 = R13 (best structure: 512 threads = 8 narrow waves
// 1M x 8N, wave tile 64x32, 64 rows/block, zA 32KB swizzled, (512,4))
// with ONE change: #pragma unroll 2 on every k-loop. R13's full unroll let
// the scheduler hoist up to 16 B-loads (64 regs) across the unrolled body,
// busting the 64-arch-reg cap -> ~46MB scratch spill traffic. unroll 2
// bounds in-flight state to ~48 regs (2x(4 A-frags + 2 B-frags)) while
// keeping 16 independent MFMAs per iteration pair.
// R14/R15's wave-independent variant (zero barriers) regressed to 159us:
// single-wave blocks can't hide L2 latency (occupancy capped, MfmaUtil 6%).
// ---------------------------------------------------------------------------
__global__ __launch_bounds__(512, 4) void ficonn_mfma_kernel(
    const float* __restrict__ x,
    const u16* __restrict__ P1, const u16* __restrict__ P2,
    const u16* __restrict__ P3, const u16* __restrict__ P4,
    const float* __restrict__ al1, const float* __restrict__ be1,
    const float* __restrict__ al2, const float* __restrict__ be2,
    const float* __restrict__ bias, float* __restrict__ out)
{
    __shared__ __align__(16) char zA[32768];   // [64 rows][256 cols] bf16, swizzled

    const int tid  = threadIdx.x;
    const int lane = tid & 63;
    const int wv   = tid >> 6;        // 0..7 (N-split)
    const int l16  = lane & 15;
    const int kg   = lane >> 4;
    const int nb   = wv * 32;         // col base, stages 1-3
    const size_t rowBase = (size_t)blockIdx.x * 64;

    const int jf = wv * 16 + l16;     // this thread's complex feature
    const float av1 = 0.5f * fminf(fmaxf(al1[jf], 0.f), 10.f);
    const float bv1 = fminf(fmaxf(be1[jf], 0.f), 10.f);
    const float av2 = 0.5f * fminf(fmaxf(al2[jf], 0.f), 10.f);
    const float bv2 = fminf(fmaxf(be2[jf], 0.f), 10.f);

    // ---- stage x tile (64 rows x 128 cols fp32) into zA as bf16, coalesced --
    {
        const float4* xg = (const float4*)(x + rowBase * 128);
        #pragma unroll
        for (int i = 0; i < 4; ++i) {
            const int idx = tid + i * 512;        // 0..2047
            const int row = idx >> 5;             // 32 float4 per row
            const int c4  = idx & 31;
            float4 f = xg[idx];
            uint2 v;
            v.x = (unsigned)f2bf(f.x) | ((unsigned)f2bf(f.y) << 16);
            v.y = (unsigned)f2bf(f.z) | ((unsigned)f2bf(f.w) << 16);
            const unsigned byte = ((unsigned)(row * 512 + c4 * 8)) ^ ((unsigned)(row & 31) << 4);
            *(uint2*)(zA + byte) = v;
        }
    }
    __syncthreads();

    f32x4 acc[4][2];

    // ================= stage 1: A = zA (x bf16), B = P1, K=128 ==============
    #pragma unroll
    for (int mt = 0; mt < 4; ++mt)
        #pragma unroll
        for (int nt = 0; nt < 2; ++nt) acc[mt][nt] = (f32x4){0.f, 0.f, 0.f, 0.f};

    #pragma unroll 2
    for (int ksl = 0; ksl < 4; ++ksl) {
        const int k0 = ksl * 32 + kg * 8;
        bf16x8 A[4];
        #pragma unroll
        for (int mt = 0; mt < 4; ++mt) {
            const int row = mt * 16 + l16;
            const unsigned byte = ((unsigned)(row * 512 + k0 * 2)) ^ ((unsigned)(row & 31) << 4);
            A[mt] = *(const bf16x8*)(zA + byte);
        }
        #pragma unroll
        for (int nt = 0; nt < 2; ++nt) {
            bf16x8 Bf = *(const bf16x8*)&P1[(nb + nt * 16 + l16) * 128 + k0];
            #pragma unroll
            for (int mt = 0; mt < 4; ++mt)
                acc[mt][nt] = __builtin_amdgcn_mfma_f32_16x16x32_bf16(A[mt], Bf, acc[mt][nt], 0, 0, 0);
        }
    }
    __syncthreads();   // all x reads done before overwrite

    // nofu1 + store to zA (wave covers cols [nb, nb+32): Re | Im of feature jf)
    #pragma unroll
    for (int mt = 0; mt < 4; ++mt)
        #pragma unroll
        for (int r = 0; r < 4; ++r) {
            float re = acc[mt][0][r], im = acc[mt][1][r];
            float I = fmaf(re, re, fmaf(im, im, 1e-8f));
            float fct = __expf(-av1 / fmaf(bv1, I, 1.f));
            re *= fct; im *= fct;
            const int row = mt * 16 + kg * 4 + r;
            const int colRe = nb + l16;
            const unsigned sw = (unsigned)(row & 31) << 4;
            *(u16*)(zA + (((unsigned)(row * 512 + colRe * 2)) ^ sw)) = f2bf(re);
            *(u16*)(zA + (((unsigned)(row * 512 + (colRe + 16) * 2)) ^ sw)) = f2bf(im);
        }
    __syncthreads();

    // ================= stage 2: A = zA, B = P2, K=256 =======================
    #pragma unroll
    for (int mt = 0; mt < 4; ++mt)
        #pragma unroll
        for (int nt = 0; nt < 2; ++nt) acc[mt][nt] = (f32x4){0.f, 0.f, 0.f, 0.f};

    #pragma unroll 2
    for (int ks = 0; ks < 8; ++ks) {
        const int k0 = ks * 32 + kg * 8;
        bf16x8 A[4];
        #pragma unroll
        for (int mt = 0; mt < 4; ++mt) {
            const int row = mt * 16 + l16;
            const unsigned byte = ((unsigned)(row * 512 + k0 * 2)) ^ ((unsigned)(row & 31) << 4);
            A[mt] = *(const bf16x8*)(zA + byte);
        }
        #pragma unroll
        for (int nt = 0; nt < 2; ++nt) {
            bf16x8 Bf = *(const bf16x8*)&P2[(nb + nt * 16 + l16) * 256 + k0];
            #pragma unroll
            for (int mt = 0; mt < 4; ++mt)
                acc[mt][nt] = __builtin_amdgcn_mfma_f32_16x16x32_bf16(A[mt], Bf, acc[mt][nt], 0, 0, 0);
        }
    }
    __syncthreads();   // all zA reads done before overwrite

    // nofu2 + store to zA
    #pragma unroll
    for (int mt = 0; mt < 4; ++mt)
        #pragma unroll
        for (int r = 0; r < 4; ++r) {
            float re = acc[mt][0][r], im = acc[mt][1][r];
            float I = fmaf(re, re, fmaf(im, im, 1e-8f));
            float fct = __expf(-av2 / fmaf(bv2, I, 1.f));
            re *= fct; im *= fct;
            const int row = mt * 16 + kg * 4 + r;
            const int colRe = nb + l16;
            const unsigned sw = (unsigned)(row & 31) << 4;
            *(u16*)(zA + (((unsigned)(row * 512 + colRe * 2)) ^ sw)) = f2bf(re);
            *(u16*)(zA + (((unsigned)(row * 512 + (colRe + 16) * 2)) ^ sw)) = f2bf(im);
        }
    __syncthreads();

    // ================= stage 3: A = zA, B = P3, K=256 (no nofu) =============
    #pragma unroll
    for (int mt = 0; mt < 4; ++mt)
        #pragma unroll
        for (int nt = 0; nt < 2; ++nt) acc[mt][nt] = (f32x4){0.f, 0.f, 0.f, 0.f};

    #pragma unroll 2
    for (int ks = 0; ks < 8; ++ks) {
        const int k0 = ks * 32 + kg * 8;
        bf16x8 A[4];
        #pragma unroll
        for (int mt = 0; mt < 4; ++mt) {
            const int row = mt * 16 + l16;
            const unsigned byte = ((unsigned)(row * 512 + k0 * 2)) ^ ((unsigned)(row & 31) << 4);
            A[mt] = *(const bf16x8*)(zA + byte);
        }
        #pragma unroll
        for (int nt = 0; nt < 2; ++nt) {
            bf16x8 Bf = *(const bf16x8*)&P3[(nb + nt * 16 + l16) * 256 + k0];
            #pragma unroll
            for (int mt = 0; mt < 4; ++mt)
                acc[mt][nt] = __builtin_amdgcn_mfma_f32_16x16x32_bf16(A[mt], Bf, acc[mt][nt], 0, 0, 0);
        }
    }
    __syncthreads();

    // store z3 (plain) to zA
    #pragma unroll
    for (int mt = 0; mt < 4; ++mt)
        #pragma unroll
        for (int r = 0; r < 4; ++r) {
            const int row = mt * 16 + kg * 4 + r;
            const int colRe = nb + l16;
            const unsigned sw = (unsigned)(row & 31) << 4;
            *(u16*)(zA + (((unsigned)(row * 512 + colRe * 2)) ^ sw)) = f2bf(acc[mt][0][r]);
            *(u16*)(zA + (((unsigned)(row * 512 + (colRe + 16) * 2)) ^ sw)) = f2bf(acc[mt][1][r]);
        }
    __syncthreads();

    // ================= final: A = zA, B = P4 [128 cols][256 k], 16 cols/wave =
    f32x4 facc[4];
    #pragma unroll
    for (int mt = 0; mt < 4; ++mt) facc[mt] = (f32x4){0.f, 0.f, 0.f, 0.f};

    const int nb2 = wv * 16;
    #pragma unroll 2
    for (int ks = 0; ks < 8; ++ks) {
        const int k0 = ks * 32 + kg * 8;
        bf16x8 A[4];
        #pragma unroll
        for (int mt = 0; mt < 4; ++mt) {
            const int row = mt * 16 + l16;
            const unsigned byte = ((unsigned)(row * 512 + k0 * 2)) ^ ((unsigned)(row & 31) << 4);
            A[mt] = *(const bf16x8*)(zA + byte);
        }
        bf16x8 Bf = *(const bf16x8*)&P4[(nb2 + l16) * 256 + k0];
        #pragma unroll
        for (int mt = 0; mt < 4; ++mt)
            facc[mt] = __builtin_amdgcn_mfma_f32_16x16x32_bf16(A[mt], Bf, facc[mt], 0, 0, 0);
    }

    const float bcol = bias[nb2 + l16];
    #pragma unroll
    for (int mt = 0; mt < 4; ++mt)
        #pragma unroll
        for (int r = 0; r < 4; ++r) {
            const size_t row = rowBase + mt * 16 + kg * 4 + r;
            out[row * 128 + nb2 + l16] = facc[mt][r] + bcol;
        }
}

extern "C" void kernel_launch(void* const* d_in, const int* in_sizes, int n_in,
                              void* d_out, int out_size, void* d_ws, size_t ws_size,
                              hipStream_t stream)
{
    const float* x      = (const float*)d_in[0];
    const float* inph   = (const float*)d_in[1];
    const float* mzi1   = (const float*)d_in[2];
    const float* outph1 = (const float*)d_in[3];
    const float* alpha1 = (const float*)d_in[4];
    const float* beta1  = (const float*)d_in[5];
    const float* mzi2   = (const float*)d_in[6];
    const float* outph2 = (const float*)d_in[7];
    const float* alpha2 = (const float*)d_in[8];
    const float* beta2  = (const float*)d_in[9];
    const float* mzi3   = (const float*)d_in[10];
    const float* outph3 = (const float*)d_in[11];
    const float* W      = (const float*)d_in[12];
    const float* bias   = (const float*)d_in[13];

    const int B = in_sizes[0] / 128;

    // ws layout
    float4* trig = (float4*)d_ws;                          // 3*128*64*16 = 393216 B
    u16* P1 = (u16*)((char*)d_ws + 393216);                // 65536 B
    u16* P2 = P1 + 32768;                                  // 131072 B
    u16* P3 = P2 + 65536;                                  // 131072 B
    u16* P4 = P3 + 65536;                                  // 65536 B

    prep_trig_kernel<<<512, 128, 0, stream>>>(mzi1, mzi2, mzi3, W, trig, P4);
    build_pack_kernel<<<384, 64, 0, stream>>>(inph, outph1, outph2, outph3, trig, P1, P2, P3);
    ficonn_mfma_kernel<<<B / 64, 512, 0, stream>>>(
        x, P1, P2, P3, P4, alpha1, beta1, alpha2, beta2, bias, (float*)d_out);
}

// Round 17
// 86.234 us; speedup vs baseline: 1.5636x; 1.0003x over previous
//
#include <hip/hip_runtime.h>
#include <math.h>

typedef __attribute__((ext_vector_type(8))) short bf16x8;
typedef __attribute__((ext_vector_type(4))) float f32x4;
typedef unsigned short u16;

__device__ __forceinline__ unsigned short f2bf(float f) {
    unsigned u = __builtin_bit_cast(unsigned, f);
    u += 0x7fffu + ((u >> 16) & 1u);          // round-to-nearest-even
    return (unsigned short)(u >> 16);
}

// ---------------------------------------------------------------------------
// Prep 1: sin/cos table for all MZIs of all 3 meshes (+ pack P4 from W).
// ---------------------------------------------------------------------------
__global__ __launch_bounds__(128) void prep_trig_kernel(
    const float* __restrict__ mzi1, const float* __restrict__ mzi2,
    const float* __restrict__ mzi3, const float* __restrict__ W,
    float4* __restrict__ trig, u16* __restrict__ P4)
{
    const int b = blockIdx.x, t = threadIdx.x;
    if (b < 384) {
        if (t >= 64) return;
        const int s = b >> 7, L = b & 127;
        const float* mzi = (s == 0) ? mzi1 : ((s == 1) ? mzi2 : mzi3);
        const int start = L & 1;
        const int m = (128 - start) >> 1;
        float4 v = make_float4(1.f, 0.f, 1.f, 0.f);
        if (t < m) {
            const int off = (L >> 1) * 254 + start * 128 + 2 * t;
            float th = mzi[off], ph = mzi[off + 1];
            float st, ct, sp, cp;
            __sincosf(th, &st, &ct);
            __sincosf(ph, &sp, &cp);
            v = make_float4(ct, st, cp, sp);
        }
        trig[b * 64 + t] = v;
    } else {
        const int n = b - 384;           // output col 0..127
        const int j = t;                  // complex feature 0..127
        const int rre = ((j >> 4) * 32) + (j & 15);
        P4[n * 256 + rre]      = f2bf(W[n * 256 + j]);
        P4[n * 256 + rre + 16] = f2bf(W[n * 256 + j + 128]);
    }
}

// ---------------------------------------------------------------------------
// Prep 2: build row r of mesh s via register+shuffle layer composition,
// then pack to bf16 weight matrices in the block-16 interleaved real form.
// ---------------------------------------------------------------------------
__global__ __launch_bounds__(64) void build_pack_kernel(
    const float* __restrict__ inph,
    const float* __restrict__ outph1, const float* __restrict__ outph2,
    const float* __restrict__ outph3,
    const float4* __restrict__ trig,
    u16* __restrict__ P1, u16* __restrict__ P2, u16* __restrict__ P3)
{
    const int s = blockIdx.x >> 7, r = blockIdx.x & 127, t = threadIdx.x;
    const float4* tg = trig + s * 128 * 64;

    float2 a = make_float2(0.f, 0.f), b2 = make_float2(0.f, 0.f);
    if (s == 0) {
        float sp, cp; __sincosf(inph[r], &sp, &cp);
        if (2 * t == r)     a  = make_float2(cp, sp);
        if (2 * t + 1 == r) b2 = make_float2(cp, sp);
    } else {
        if (2 * t == r)     a.x  = 1.f;
        if (2 * t + 1 == r) b2.x = 1.f;
    }

    float4 tv[4];
    #pragma unroll
    for (int i = 0; i < 4; ++i) tv[i] = tg[i * 64 + t];

    #pragma unroll 4
    for (int L = 0; L < 128; ++L) {
        const float4 c = tv[L & 3];
        if (L < 124) tv[L & 3] = tg[(L + 4) * 64 + t];
        if ((L & 1) == 0) {
            float pr = c.x * (a.x * c.z - a.y * c.w) + c.y * b2.x;
            float pi = c.x * (a.x * c.w + a.y * c.z) + c.y * b2.y;
            float qr = c.y * a.x - c.x * (b2.x * c.z + b2.y * c.w);
            float qi = c.y * a.y - c.x * (b2.y * c.z - b2.x * c.w);
            a = make_float2(pr, pi); b2 = make_float2(qr, qi);
        } else {
            float2 an;
            an.x = __shfl_down(a.x, 1); an.y = __shfl_down(a.y, 1);
            float pr = c.x * (b2.x * c.z - b2.y * c.w) + c.y * an.x;
            float pi = c.x * (b2.x * c.w + b2.y * c.z) + c.y * an.y;
            float qr = c.y * b2.x - c.x * (an.x * c.z + an.y * c.w);
            float qi = c.y * b2.y - c.x * (an.y * c.z - an.x * c.w);
            if (t < 63) b2 = make_float2(pr, pi);
            float2 qs;
            qs.x = __shfl_up(qr, 1); qs.y = __shfl_up(qi, 1);
            if (t >= 1) a = qs;
        }
    }

    const float* outph = (s == 0) ? outph1 : ((s == 1) ? outph2 : outph3);
    #pragma unroll
    for (int h = 0; h < 2; ++h) {
        const int j = 2 * t + h;
        float2 w = h ? b2 : a;
        float sp, cp; __sincosf(outph[j], &sp, &cp);
        const float wr = w.x * cp - w.y * sp;
        const float wi = w.x * sp + w.y * cp;
        const int cre = ((j >> 4) * 32) + (j & 15);
        if (s == 0) {
            P1[cre * 128 + r]        = f2bf(wr);
            P1[(cre + 16) * 128 + r] = f2bf(wi);
        } else {
            u16* P = (s == 1) ? P2 : P3;
            const int rre = ((r >> 4) * 32) + (r & 15);
            P[cre * 256 + rre]             = f2bf(wr);
            P[cre * 256 + rre + 16]        = f2bf(-wi);
            P[(cre + 16) * 256 + rre]      = f2bf(wi);
            P[(cre + 16) * 256 + rre + 16] = f2bf(wr);
        }
    }
}

// ---------------------------------------------------------------------------
// Main fused kernel. R17 = R16 (spill-free: 512 threads = 8 narrow waves
// 1M x 8N, wave tile 64x32, 64 rows/block, unroll-2 k-loops, (512,4))
// with ONE change: DOUBLE-BUFFERED zA (2 x 32KB). Each stage reads buffer A
// and writes buffer B, so the "reads-done-before-overwrite" barrier
// disappears: 4 __syncthreads instead of 8. Register demand unchanged
// (no held state); LDS 64KB x 2 blocks = 128 <= 160KB so occupancy holds.
// R16 post-mortem: WRITE == output exactly (spill gone), MfmaUtil 13%,
// VALUBusy 28% -> the 8 barrier drains were the dominant remaining stall.
// ---------------------------------------------------------------------------
__global__ __launch_bounds__(512, 4) void ficonn_mfma_kernel(
    const float* __restrict__ x,
    const u16* __restrict__ P1, const u16* __restrict__ P2,
    const u16* __restrict__ P3, const u16* __restrict__ P4,
    const float* __restrict__ al1, const float* __restrict__ be1,
    const float* __restrict__ al2, const float* __restrict__ be2,
    const float* __restrict__ bias, float* __restrict__ out)
{
    __shared__ __align__(16) char zBuf[2][32768];  // [64 rows][256 cols] bf16 each, swizzled
    char* const z0 = zBuf[0];
    char* const z1 = zBuf[1];

    const int tid  = threadIdx.x;
    const int lane = tid & 63;
    const int wv   = tid >> 6;        // 0..7 (N-split)
    const int l16  = lane & 15;
    const int kg   = lane >> 4;
    const int nb   = wv * 32;         // col base, stages 1-3
    const size_t rowBase = (size_t)blockIdx.x * 64;

    const int jf = wv * 16 + l16;     // this thread's complex feature
    const float av1 = 0.5f * fminf(fmaxf(al1[jf], 0.f), 10.f);
    const float bv1 = fminf(fmaxf(be1[jf], 0.f), 10.f);
    const float av2 = 0.5f * fminf(fmaxf(al2[jf], 0.f), 10.f);
    const float bv2 = fminf(fmaxf(be2[jf], 0.f), 10.f);

    // ---- stage x tile (64 rows x 128 cols fp32) into z0 as bf16, coalesced --
    {
        const float4* xg = (const float4*)(x + rowBase * 128);
        #pragma unroll
        for (int i = 0; i < 4; ++i) {
            const int idx = tid + i * 512;        // 0..2047
            const int row = idx >> 5;             // 32 float4 per row
            const int c4  = idx & 31;
            float4 f = xg[idx];
            uint2 v;
            v.x = (unsigned)f2bf(f.x) | ((unsigned)f2bf(f.y) << 16);
            v.y = (unsigned)f2bf(f.z) | ((unsigned)f2bf(f.w) << 16);
            const unsigned byte = ((unsigned)(row * 512 + c4 * 8)) ^ ((unsigned)(row & 31) << 4);
            *(uint2*)(z0 + byte) = v;
        }
    }
    __syncthreads();    // B1: x staged in z0

    f32x4 acc[4][2];

    // ================= stage 1: read z0 (x), B = P1, K=128 -> write z1 ======
    #pragma unroll
    for (int mt = 0; mt < 4; ++mt)
        #pragma unroll
        for (int nt = 0; nt < 2; ++nt) acc[mt][nt] = (f32x4){0.f, 0.f, 0.f, 0.f};

    #pragma unroll 2
    for (int ksl = 0; ksl < 4; ++ksl) {
        const int k0 = ksl * 32 + kg * 8;
        bf16x8 A[4];
        #pragma unroll
        for (int mt = 0; mt < 4; ++mt) {
            const int row = mt * 16 + l16;
            const unsigned byte = ((unsigned)(row * 512 + k0 * 2)) ^ ((unsigned)(row & 31) << 4);
            A[mt] = *(const bf16x8*)(z0 + byte);
        }
        #pragma unroll
        for (int nt = 0; nt < 2; ++nt) {
            bf16x8 Bf = *(const bf16x8*)&P1[(nb + nt * 16 + l16) * 128 + k0];
            #pragma unroll
            for (int mt = 0; mt < 4; ++mt)
                acc[mt][nt] = __builtin_amdgcn_mfma_f32_16x16x32_bf16(A[mt], Bf, acc[mt][nt], 0, 0, 0);
        }
    }

    // nofu1 + store to z1 (no barrier needed: different buffer)
    #pragma unroll
    for (int mt = 0; mt < 4; ++mt)
        #pragma unroll
        for (int r = 0; r < 4; ++r) {
            float re = acc[mt][0][r], im = acc[mt][1][r];
            float I = fmaf(re, re, fmaf(im, im, 1e-8f));
            float fct = __expf(-av1 / fmaf(bv1, I, 1.f));
            re *= fct; im *= fct;
            const int row = mt * 16 + kg * 4 + r;
            const int colRe = nb + l16;
            const unsigned sw = (unsigned)(row & 31) << 4;
            *(u16*)(z1 + (((unsigned)(row * 512 + colRe * 2)) ^ sw)) = f2bf(re);
            *(u16*)(z1 + (((unsigned)(row * 512 + (colRe + 16) * 2)) ^ sw)) = f2bf(im);
        }
    __syncthreads();    // B2: z1 complete

    // ================= stage 2: read z1, B = P2, K=256 -> write z0 ==========
    #pragma unroll
    for (int mt = 0; mt < 4; ++mt)
        #pragma unroll
        for (int nt = 0; nt < 2; ++nt) acc[mt][nt] = (f32x4){0.f, 0.f, 0.f, 0.f};

    #pragma unroll 2
    for (int ks = 0; ks < 8; ++ks) {
        const int k0 = ks * 32 + kg * 8;
        bf16x8 A[4];
        #pragma unroll
        for (int mt = 0; mt < 4; ++mt) {
            const int row = mt * 16 + l16;
            const unsigned byte = ((unsigned)(row * 512 + k0 * 2)) ^ ((unsigned)(row & 31) << 4);
            A[mt] = *(const bf16x8*)(z1 + byte);
        }
        #pragma unroll
        for (int nt = 0; nt < 2; ++nt) {
            bf16x8 Bf = *(const bf16x8*)&P2[(nb + nt * 16 + l16) * 256 + k0];
            #pragma unroll
            for (int mt = 0; mt < 4; ++mt)
                acc[mt][nt] = __builtin_amdgcn_mfma_f32_16x16x32_bf16(A[mt], Bf, acc[mt][nt], 0, 0, 0);
        }
    }

    // nofu2 + store to z0
    #pragma unroll
    for (int mt = 0; mt < 4; ++mt)
        #pragma unroll
        for (int r = 0; r < 4; ++r) {
            float re = acc[mt][0][r], im = acc[mt][1][r];
            float I = fmaf(re, re, fmaf(im, im, 1e-8f));
            float fct = __expf(-av2 / fmaf(bv2, I, 1.f));
            re *= fct; im *= fct;
            const int row = mt * 16 + kg * 4 + r;
            const int colRe = nb + l16;
            const unsigned sw = (unsigned)(row & 31) << 4;
            *(u16*)(z0 + (((unsigned)(row * 512 + colRe * 2)) ^ sw)) = f2bf(re);
            *(u16*)(z0 + (((unsigned)(row * 512 + (colRe + 16) * 2)) ^ sw)) = f2bf(im);
        }
    __syncthreads();    // B3: z0 complete

    // ================= stage 3: read z0, B = P3, K=256 -> write z1 ==========
    #pragma unroll
    for (int mt = 0; mt < 4; ++mt)
        #pragma unroll
        for (int nt = 0; nt < 2; ++nt) acc[mt][nt] = (f32x4){0.f, 0.f, 0.f, 0.f};

    #pragma unroll 2
    for (int ks = 0; ks < 8; ++ks) {
        const int k0 = ks * 32 + kg * 8;
        bf16x8 A[4];
        #pragma unroll
        for (int mt = 0; mt < 4; ++mt) {
            const int row = mt * 16 + l16;
            const unsigned byte = ((unsigned)(row * 512 + k0 * 2)) ^ ((unsigned)(row & 31) << 4);
            A[mt] = *(const bf16x8*)(z0 + byte);
        }
        #pragma unroll
        for (int nt = 0; nt < 2; ++nt) {
            bf16x8 Bf = *(const bf16x8*)&P3[(nb + nt * 16 + l16) * 256 + k0];
            #pragma unroll
            for (int mt = 0; mt < 4; ++mt)
                acc[mt][nt] = __builtin_amdgcn_mfma_f32_16x16x32_bf16(A[mt], Bf, acc[mt][nt], 0, 0, 0);
        }
    }

    // store z3 (plain) to z1
    #pragma unroll
    for (int mt = 0; mt < 4; ++mt)
        #pragma unroll
        for (int r = 0; r < 4; ++r) {
            const int row = mt * 16 + kg * 4 + r;
            const int colRe = nb + l16;
            const unsigned sw = (unsigned)(row & 31) << 4;
            *(u16*)(z1 + (((unsigned)(row * 512 + colRe * 2)) ^ sw)) = f2bf(acc[mt][0][r]);
            *(u16*)(z1 + (((unsigned)(row * 512 + (colRe + 16) * 2)) ^ sw)) = f2bf(acc[mt][1][r]);
        }
    __syncthreads();    // B4: z1 complete

    // ================= final: read z1, B = P4 [128 cols][256 k] =============
    f32x4 facc[4];
    #pragma unroll
    for (int mt = 0; mt < 4; ++mt) facc[mt] = (f32x4){0.f, 0.f, 0.f, 0.f};

    const int nb2 = wv * 16;
    #pragma unroll 2
    for (int ks = 0; ks < 8; ++ks) {
        const int k0 = ks * 32 + kg * 8;
        bf16x8 A[4];
        #pragma unroll
        for (int mt = 0; mt < 4; ++mt) {
            const int row = mt * 16 + l16;
            const unsigned byte = ((unsigned)(row * 512 + k0 * 2)) ^ ((unsigned)(row & 31) << 4);
            A[mt] = *(const bf16x8*)(z1 + byte);
        }
        bf16x8 Bf = *(const bf16x8*)&P4[(nb2 + l16) * 256 + k0];
        #pragma unroll
        for (int mt = 0; mt < 4; ++mt)
            facc[mt] = __builtin_amdgcn_mfma_f32_16x16x32_bf16(A[mt], Bf, facc[mt], 0, 0, 0);
    }

    const float bcol = bias[nb2 + l16];
    #pragma unroll
    for (int mt = 0; mt < 4; ++mt)
        #pragma unroll
        for (int r = 0; r < 4; ++r) {
            const size_t row = rowBase + mt * 16 + kg * 4 + r;
            out[row * 128 + nb2 + l16] = facc[mt][r] + bcol;
        }
}

extern "C" void kernel_launch(void* const* d_in, const int* in_sizes, int n_in,
                              void* d_out, int out_size, void* d_ws, size_t ws_size,
                              hipStream_t stream)
{
    const float* x      = (const float*)d_in[0];
    const float* inph   = (const float*)d_in[1];
    const float* mzi1   = (const float*)d_in[2];
    const float* outph1 = (const float*)d_in[3];
    const float* alpha1 = (const float*)d_in[4];
    const float* beta1  = (const float*)d_in[5];
    const float* mzi2   = (const float*)d_in[6];
    const float* outph2 = (const float*)d_in[7];
    const float* alpha2 = (const float*)d_in[8];
    const float* beta2  = (const float*)d_in[9];
    const float* mzi3   = (const float*)d_in[10];
    const float* outph3 = (const float*)d_in[11];
    const float* W      = (const float*)d_in[12];
    const float* bias   = (const float*)d_in[13];

    const int B = in_sizes[0] / 128;

    // ws layout
    float4* trig = (float4*)d_ws;                          // 3*128*64*16 = 393216 B
    u16* P1 = (u16*)((char*)d_ws + 393216);                // 65536 B
    u16* P2 = P1 + 32768;                                  // 131072 B
    u16* P3 = P2 + 65536;                                  // 131072 B
    u16* P4 = P3 + 65536;                                  // 65536 B

    prep_trig_kernel<<<512, 128, 0, stream>>>(mzi1, mzi2, mzi3, W, trig, P4);
    build_pack_kernel<<<384, 64, 0, stream>>>(inph, outph1, outph2, outph3, trig, P1, P2, P3);
    ficonn_mfma_kernel<<<B / 64, 512, 0, stream>>>(
        x, P1, P2, P3, P4, alpha1, beta1, alpha2, beta2, bias, (float*)d_out);
}